// Round 4
// baseline (218.709 us; speedup 1.0000x reference)
//
#include <hip/hip_runtime.h>
#include <hip/hip_bf16.h>

typedef unsigned short u16;
typedef __attribute__((ext_vector_type(8))) short bf16x8;
typedef __attribute__((ext_vector_type(4))) float f32x4;

#define MFMA16(a, b, c) __builtin_amdgcn_mfma_f32_16x16x32_bf16((a), (b), (c), 0, 0, 0)

#define NB 64
#define ND 1024
#define NQ 128
#define NE 300
#define NH 256
#define KP 320
#define QETN 304
#define DOC_W 624

static __device__ __forceinline__ u16 f2bf(float f) {
  union { float f; unsigned i; } x; x.f = f;
  return (u16)((x.i + 0x7FFFu + ((x.i >> 16) & 1u)) >> 16);
}

static __device__ __forceinline__ bf16x8 cvt8(const float* p) {
  float4 f0 = *(const float4*)p;
  float4 f1 = *(const float4*)(p + 4);
  union { bf16x8 v; u16 u[8]; } r;
  r.u[0] = f2bf(f0.x); r.u[1] = f2bf(f0.y); r.u[2] = f2bf(f0.z); r.u[3] = f2bf(f0.w);
  r.u[4] = f2bf(f1.x); r.u[5] = f2bf(f1.y); r.u[6] = f2bf(f1.z); r.u[7] = f2bf(f1.w);
  return r.v;
}

// ---- Wt[n][k] = bf16(proj_w[k][n]), zero rows for k in [300,320) ----
__global__ void k_prepw(const float* __restrict__ w, u16* __restrict__ wt) {
  int idx = blockIdx.x * 256 + threadIdx.x;
  if (idx >= NH * KP) return;
  int n = idx / KP, k = idx % KP;
  wt[idx] = (k < NE) ? f2bf(w[k * NH + n]) : (u16)0;
}

// ---- f32 embedding gather -> f32 out slice (300 cols, arbitrary row stride) ----
__global__ void k_embed(const int* __restrict__ tok, const float* __restrict__ table,
                        float* __restrict__ out_f, long out_stride, int nrows) {
  int idx = blockIdx.x * 256 + threadIdx.x;
  int row = idx / 75, j = idx % 75;
  if (row >= nrows) return;
  int k = j * 4;
  float4 v = {0.f, 0.f, 0.f, 0.f};
  int t = tok[row];
  if (t != 0) v = *(const float4*)(table + (long)t * NE + k);
  *(float4*)(out_f + (long)row * out_stride + k) = v;
}

// ---- ner(8)/pos(12)/fea(4) -> doc_out cols 600:624, f32 ----
__global__ void k_extras(const int* __restrict__ ner, const int* __restrict__ pos,
                         const float* __restrict__ fea,
                         const float* __restrict__ ner_emb, const float* __restrict__ pos_emb,
                         float* __restrict__ doc_out) {
  int idx = blockIdx.x * 256 + threadIdx.x;
  if (idx >= NB * ND * 24) return;
  int row = idx / 24, c = idx % 24;
  float v;
  if (c < 8)       { int t = ner[row]; v = t ? ner_emb[t * 8 + c] : 0.f; }
  else if (c < 20) { int t = pos[row]; v = t ? pos_emb[t * 12 + (c - 8)] : 0.f; }
  else             { v = fea[(long)row * 4 + (c - 20)]; }
  doc_out[(long)row * DOC_W + 600 + c] = v;
}

// ---- qeT[b][n][k] = bf16(q_out[b*128+k][n]), n in [300,304) -> 0 ----
__global__ void k_qet(const float* __restrict__ qo, u16* __restrict__ qet) {
  int idx = blockIdx.x * 256 + threadIdx.x;
  if (idx >= NB * QETN * NQ) return;
  int k = idx & 127;
  int rem = idx >> 7;
  int n = rem % QETN, b = rem / QETN;
  u16 v = 0;
  if (n < NE) v = f2bf(qo[((long)(b * NQ + k)) * NE + n]);
  qet[idx] = v;
}

// ---- P = relu(X @ W + b) -> bf16. X: f32 rows (stride xstride), K-tail x Wt==0 ----
__launch_bounds__(256)
__global__ void k_proj(const float* __restrict__ X, long xstride,
                       const u16* __restrict__ Wt, const float* __restrict__ bias,
                       u16* __restrict__ P) {
  int l = threadIdx.x & 63, w = threadIdx.x >> 6;
  int lr = l & 15, lg = l >> 4;
  int bm = blockIdx.x * 64 + (w & 1) * 32;
  int bn = blockIdx.y * 64 + (w >> 1) * 32;
  f32x4 acc[2][2] = {};
  const float* xp0 = X + (long)(bm + lr) * xstride + 8 * lg;
  const float* xp1 = xp0 + 16 * xstride;
  const u16* wp = Wt + (long)(bn + lr) * KP + 8 * lg;
#pragma unroll
  for (int ks = 0; ks < KP; ks += 32) {
    bf16x8 a0 = cvt8(xp0 + ks);
    bf16x8 a1 = cvt8(xp1 + ks);
    bf16x8 b0 = *(const bf16x8*)(wp + ks);
    bf16x8 b1 = *(const bf16x8*)(wp + 16 * KP + ks);
    acc[0][0] = MFMA16(a0, b0, acc[0][0]);
    acc[1][0] = MFMA16(a1, b0, acc[1][0]);
    acc[0][1] = MFMA16(a0, b1, acc[0][1]);
    acc[1][1] = MFMA16(a1, b1, acc[1][1]);
  }
#pragma unroll
  for (int mt = 0; mt < 2; ++mt)
#pragma unroll
    for (int nt = 0; nt < 2; ++nt) {
      int col = bn + nt * 16 + lr;
      float bv = bias[col];
#pragma unroll
      for (int r = 0; r < 4; ++r) {
        int row = bm + mt * 16 + 4 * lg + r;
        float v = acc[mt][nt][r] + bv;
        v = v > 0.f ? v : 0.f;
        P[(long)row * NH + col] = f2bf(v);
      }
    }
}

// ---- attention: scores -> softmax(q) -> prealign -> doc_out cols 300:600 (f32) ----
__launch_bounds__(256)
__global__ void k_attn(const u16* __restrict__ dP, const u16* __restrict__ qP,
                       const u16* __restrict__ qeT, float* __restrict__ doc_out) {
  __shared__ u16 p_lds[128][136];
  int b = blockIdx.y, chunk = blockIdx.x;
  int l = threadIdx.x & 63, w = threadIdx.x >> 6;
  int lr = l & 15, lg = l >> 4;
  int rowbase = chunk * 128 + w * 32;  // local row within D

  // phase 1: scores S[32 rows][128 q] per wave (K = H = 256)
  f32x4 s[2][8] = {};
  const u16* dpp = dP + ((long)(b * ND + rowbase + lr)) * NH + 8 * lg;
  const u16* qpp = qP + ((long)(b * NQ + lr)) * NH + 8 * lg;
#pragma unroll
  for (int ks = 0; ks < NH; ks += 32) {
    bf16x8 a0 = *(const bf16x8*)(dpp + ks);
    bf16x8 a1 = *(const bf16x8*)(dpp + 16 * NH + ks);
#pragma unroll
    for (int nt = 0; nt < 8; ++nt) {
      bf16x8 bb = *(const bf16x8*)(qpp + nt * 16 * NH + ks);
      s[0][nt] = MFMA16(a0, bb, s[0][nt]);
      s[1][nt] = MFMA16(a1, bb, s[1][nt]);
    }
  }

  // phase 2: softmax over q
#pragma unroll
  for (int mt = 0; mt < 2; ++mt) {
    f32x4 mx;
#pragma unroll
    for (int r = 0; r < 4; ++r) {
      float m = s[mt][0][r];
#pragma unroll
      for (int nt = 1; nt < 8; ++nt) m = fmaxf(m, s[mt][nt][r]);
      mx[r] = m;
    }
#pragma unroll
    for (int d = 1; d < 16; d <<= 1)
#pragma unroll
      for (int r = 0; r < 4; ++r) mx[r] = fmaxf(mx[r], __shfl_xor(mx[r], d));
    f32x4 sum = {};
#pragma unroll
    for (int nt = 0; nt < 8; ++nt)
#pragma unroll
      for (int r = 0; r < 4; ++r) {
        float p = __expf(s[mt][nt][r] - mx[r]);
        s[mt][nt][r] = p;
        sum[r] += p;
      }
#pragma unroll
    for (int d = 1; d < 16; d <<= 1)
#pragma unroll
      for (int r = 0; r < 4; ++r) sum[r] += __shfl_xor(sum[r], d);
    f32x4 inv;
#pragma unroll
    for (int r = 0; r < 4; ++r) inv[r] = 1.0f / sum[r];
#pragma unroll
    for (int nt = 0; nt < 8; ++nt)
#pragma unroll
      for (int r = 0; r < 4; ++r) {
        int rl = w * 32 + mt * 16 + 4 * lg + r;
        int c = nt * 16 + lr;
        p_lds[rl][c] = f2bf(s[mt][nt][r] * inv[r]);
      }
  }
  __syncthreads();

  // phase 3: prealign = P @ query_e[b]  (K = Q = 128), cols 0..299
  const u16* qtp = qeT + (long)b * QETN * NQ;
#pragma unroll 1
  for (int nt = 0; nt < 19; ++nt) {
    f32x4 acc0 = {}, acc1 = {};
#pragma unroll
    for (int ks = 0; ks < NQ; ks += 32) {
      bf16x8 a0 = *(const bf16x8*)(&p_lds[w * 32 + lr][ks + 8 * lg]);
      bf16x8 a1 = *(const bf16x8*)(&p_lds[w * 32 + 16 + lr][ks + 8 * lg]);
      bf16x8 bb = *(const bf16x8*)(qtp + (long)(nt * 16 + lr) * NQ + ks + 8 * lg);
      acc0 = MFMA16(a0, bb, acc0);
      acc1 = MFMA16(a1, bb, acc1);
    }
    int col = nt * 16 + lr;
    if (col < NE) {
#pragma unroll
      for (int r = 0; r < 4; ++r) {
        long rl0 = (long)b * ND + chunk * 128 + w * 32 + 4 * lg + r;
        doc_out[rl0 * DOC_W + 300 + col] = acc0[r];
        doc_out[(rl0 + 16) * DOC_W + 300 + col] = acc1[r];
      }
    }
  }
}

extern "C" void kernel_launch(void* const* d_in, const int* in_sizes, int n_in,
                              void* d_out, int out_size, void* d_ws, size_t ws_size,
                              hipStream_t stream) {
  // Size-based dispatch (verified in R3: identical to dict order; kept for robustness).
  const int *query_tok = nullptr, *doc_tok = nullptr, *doc_pos = nullptr, *doc_ner = nullptr;
  const float *doc_fea = nullptr, *word_emb = nullptr, *proj_w = nullptr,
              *proj_b = nullptr, *pos_emb = nullptr, *ner_emb = nullptr;
  int n65536 = 0;
  for (int i = 0; i < n_in; ++i) {
    switch (in_sizes[i]) {
      case 15000000: word_emb  = (const float*)d_in[i]; break;  // 50000*300
      case 262144:   doc_fea   = (const float*)d_in[i]; break;  // 64*1024*4
      case 76800:    proj_w    = (const float*)d_in[i]; break;  // 300*256
      case 8192:     query_tok = (const int*)d_in[i];   break;  // 64*128
      case 256:      proj_b    = (const float*)d_in[i]; break;
      case 672:      pos_emb   = (const float*)d_in[i]; break;  // 56*12
      case 152:      ner_emb   = (const float*)d_in[i]; break;  // 19*8
      case 65536:                                               // 64*1024 ints
        if (n65536 == 0)      doc_tok = (const int*)d_in[i];
        else if (n65536 == 1) doc_pos = (const int*)d_in[i];
        else                  doc_ner = (const int*)d_in[i];
        ++n65536; break;
      default: break;
    }
  }

  // Outputs are FLOAT32 (reference computes in f32; "else float*" harness rule).
  float* out = (float*)d_out;
  float* q_out   = out;                         // [B*Q][300]
  float* doc_out = out + (size_t)NB * NQ * NE;  // [B*D][624]

  char* ws = (char*)d_ws;
  u16* Wt     = (u16*)ws; ws += (size_t)NH * KP * 2;        // 160 KB
  u16* q_proj = (u16*)ws; ws += (size_t)NB * NQ * NH * 2;   // 4 MB
  u16* d_proj = (u16*)ws; ws += (size_t)NB * ND * NH * 2;   // 32 MB
  u16* qeT    = (u16*)ws; ws += (size_t)NB * QETN * NQ * 2; // 4.75 MB

  k_prepw<<<dim3((NH * KP + 255) / 256), dim3(256), 0, stream>>>(proj_w, Wt);
  k_embed<<<dim3(NB * NQ * 75 / 256), dim3(256), 0, stream>>>(
      query_tok, word_emb, q_out, (long)NE, NB * NQ);
  k_embed<<<dim3(NB * ND * 75 / 256), dim3(256), 0, stream>>>(
      doc_tok, word_emb, doc_out, (long)DOC_W, NB * ND);
  k_extras<<<dim3(NB * ND * 24 / 256), dim3(256), 0, stream>>>(
      doc_ner, doc_pos, doc_fea, ner_emb, pos_emb, doc_out);
  k_qet<<<dim3((NB * QETN * NQ + 255) / 256), dim3(256), 0, stream>>>(q_out, qeT);
  k_proj<<<dim3(NB * NQ / 64, NH / 64), dim3(256), 0, stream>>>(
      q_out, (long)NE, Wt, proj_b, q_proj);
  k_proj<<<dim3(NB * ND / 64, NH / 64), dim3(256), 0, stream>>>(
      doc_out, (long)DOC_W, Wt, proj_b, d_proj);
  k_attn<<<dim3(ND / 128, NB), dim3(256), 0, stream>>>(d_proj, q_proj, qeT, doc_out);
}

// Round 5
// 190.286 us; speedup vs baseline: 1.1494x; 1.1494x over previous
//
#include <hip/hip_runtime.h>
#include <hip/hip_bf16.h>

typedef unsigned short u16;
typedef __attribute__((ext_vector_type(8))) short bf16x8;
typedef __attribute__((ext_vector_type(4))) float f32x4;

#define MFMA16(a, b, c) __builtin_amdgcn_mfma_f32_16x16x32_bf16((a), (b), (c), 0, 0, 0)

#define NB 64
#define ND 1024
#define NQ 128
#define NE 300
#define NH 256
#define KP 320
#define QETN 304
#define DOC_W 624

// RNE f32->bf16 via native __bf16 (compiler emits v_cvt_pk_bf16_f32; m240: don't hand-write)
static __device__ __forceinline__ u16 f2bf(float f) {
  union { __bf16 h; u16 u; } c; c.h = (__bf16)f; return c.u;
}

static __device__ __forceinline__ bf16x8 cvt8(const float* p) {
  float4 f0 = *(const float4*)p;
  float4 f1 = *(const float4*)(p + 4);
  union { bf16x8 v; u16 u[8]; } r;
  r.u[0] = f2bf(f0.x); r.u[1] = f2bf(f0.y); r.u[2] = f2bf(f0.z); r.u[3] = f2bf(f0.w);
  r.u[4] = f2bf(f1.x); r.u[5] = f2bf(f1.y); r.u[6] = f2bf(f1.z); r.u[7] = f2bf(f1.w);
  return r.v;
}

// ---- Wt[n][k] = bf16(proj_w[k][n]), zero rows for k in [300,320) ----
__global__ void k_prepw(const float* __restrict__ w, u16* __restrict__ wt) {
  int idx = blockIdx.x * 256 + threadIdx.x;
  if (idx >= NH * KP) return;
  int n = idx / KP, k = idx % KP;
  wt[idx] = (k < NE) ? f2bf(w[k * NH + n]) : (u16)0;
}

// ---- f32 embedding gather -> f32 out slice (300 cols, arbitrary row stride) ----
__global__ void k_embed(const int* __restrict__ tok, const float* __restrict__ table,
                        float* __restrict__ out_f, long out_stride, int nrows) {
  int idx = blockIdx.x * 256 + threadIdx.x;
  int row = idx / 75, j = idx % 75;
  if (row >= nrows) return;
  int k = j * 4;
  float4 v = {0.f, 0.f, 0.f, 0.f};
  int t = tok[row];
  if (t != 0) v = *(const float4*)(table + (long)t * NE + k);
  *(float4*)(out_f + (long)row * out_stride + k) = v;
}

// ---- ner(8)/pos(12)/fea(4) -> doc_out cols 600:624, f32 ----
__global__ void k_extras(const int* __restrict__ ner, const int* __restrict__ pos,
                         const float* __restrict__ fea,
                         const float* __restrict__ ner_emb, const float* __restrict__ pos_emb,
                         float* __restrict__ doc_out) {
  int idx = blockIdx.x * 256 + threadIdx.x;
  if (idx >= NB * ND * 24) return;
  int row = idx / 24, c = idx % 24;
  float v;
  if (c < 8)       { int t = ner[row]; v = t ? ner_emb[t * 8 + c] : 0.f; }
  else if (c < 20) { int t = pos[row]; v = t ? pos_emb[t * 12 + (c - 8)] : 0.f; }
  else             { v = fea[(long)row * 4 + (c - 20)]; }
  doc_out[(long)row * DOC_W + 600 + c] = v;
}

// ---- qeT[b][n][k] = bf16(q_out[b*128+k][n]) via LDS transpose; n>=300 -> 0 ----
// grid (2, NB): blockIdx.x selects k-half (64 rows), blockIdx.y = b.
__launch_bounds__(256)
__global__ void k_qet(const float* __restrict__ qo, u16* __restrict__ qet) {
  __shared__ u16 T[64][314];  // 314: odd/4 stride -> conflict-light column reads
  int b = blockIdx.y, k0 = blockIdx.x * 64;
  int tid = threadIdx.x;
  const float* src = qo + ((long)b * NQ + k0) * NE;
  for (int i = tid; i < 64 * 75; i += 256) {
    int row = i / 75, j = (i % 75) * 4;
    float4 f = *(const float4*)(src + (long)row * NE + j);
    T[row][j]     = f2bf(f.x); T[row][j + 1] = f2bf(f.y);
    T[row][j + 2] = f2bf(f.z); T[row][j + 3] = f2bf(f.w);
  }
  __syncthreads();
  u16* dst = qet + (long)b * QETN * NQ + k0;
  for (int i = tid; i < QETN * 16; i += 256) {
    int n = i / 16, kq = (i % 16) * 4;
    u16 v[4] = {0, 0, 0, 0};
    if (n < NE) {
      v[0] = T[kq][n]; v[1] = T[kq + 1][n]; v[2] = T[kq + 2][n]; v[3] = T[kq + 3][n];
    }
    *(uint2*)(dst + (long)n * NQ + kq) = *(const uint2*)v;
  }
}

// ---- P = relu(X @ W + b) -> bf16. Full-N tile: block = 64 rows x 256 cols ----
// wave w: rows (w&1)*32, cols (w>>1)*128. A f32 rows read ONCE per row.
__launch_bounds__(256)
__global__ void k_proj(const float* __restrict__ X, long xstride,
                       const u16* __restrict__ Wt, const float* __restrict__ bias,
                       u16* __restrict__ P) {
  int l = threadIdx.x & 63, w = threadIdx.x >> 6;
  int lr = l & 15, lg = l >> 4;
  int bm = blockIdx.x * 64 + (w & 1) * 32;
  int bn = (w >> 1) * 128;
  f32x4 acc[2][8] = {};
  const float* xp0 = X + (long)(bm + lr) * xstride + 8 * lg;
  const float* xp1 = xp0 + 16 * xstride;
  const u16* wp = Wt + (long)(bn + lr) * KP + 8 * lg;
#pragma unroll 2
  for (int ks = 0; ks < KP; ks += 32) {
    bf16x8 a0 = cvt8(xp0 + ks);
    bf16x8 a1 = cvt8(xp1 + ks);
#pragma unroll
    for (int nt = 0; nt < 8; ++nt) {
      bf16x8 b0 = *(const bf16x8*)(wp + (long)nt * 16 * KP + ks);
      acc[0][nt] = MFMA16(a0, b0, acc[0][nt]);
      acc[1][nt] = MFMA16(a1, b0, acc[1][nt]);
    }
  }
#pragma unroll
  for (int nt = 0; nt < 8; ++nt) {
    int col = bn + nt * 16 + lr;
    float bv = bias[col];
#pragma unroll
    for (int mt = 0; mt < 2; ++mt)
#pragma unroll
      for (int r = 0; r < 4; ++r) {
        int row = bm + mt * 16 + 4 * lg + r;
        float v = acc[mt][nt][r] + bv;
        v = v > 0.f ? v : 0.f;
        P[(long)row * NH + col] = f2bf(v);
      }
  }
}

// ---- attention: scores -> softmax(q) -> prealign -> doc_out cols 300:600 (f32) ----
__launch_bounds__(256)
__global__ void k_attn(const u16* __restrict__ dP, const u16* __restrict__ qP,
                       const u16* __restrict__ qeT, float* __restrict__ doc_out) {
  __shared__ u16 p_lds[128][136];
  int b = blockIdx.y, chunk = blockIdx.x;
  int l = threadIdx.x & 63, w = threadIdx.x >> 6;
  int lr = l & 15, lg = l >> 4;
  int rowbase = chunk * 128 + w * 32;  // local row within D

  // phase 1: scores S[32 rows][128 q] per wave (K = H = 256)
  f32x4 s[2][8] = {};
  const u16* dpp = dP + ((long)(b * ND + rowbase + lr)) * NH + 8 * lg;
  const u16* qpp = qP + ((long)(b * NQ + lr)) * NH + 8 * lg;
#pragma unroll
  for (int ks = 0; ks < NH; ks += 32) {
    bf16x8 a0 = *(const bf16x8*)(dpp + ks);
    bf16x8 a1 = *(const bf16x8*)(dpp + 16 * NH + ks);
#pragma unroll
    for (int nt = 0; nt < 8; ++nt) {
      bf16x8 bb = *(const bf16x8*)(qpp + nt * 16 * NH + ks);
      s[0][nt] = MFMA16(a0, bb, s[0][nt]);
      s[1][nt] = MFMA16(a1, bb, s[1][nt]);
    }
  }

  // phase 2: softmax over q
#pragma unroll
  for (int mt = 0; mt < 2; ++mt) {
    f32x4 mx;
#pragma unroll
    for (int r = 0; r < 4; ++r) {
      float m = s[mt][0][r];
#pragma unroll
      for (int nt = 1; nt < 8; ++nt) m = fmaxf(m, s[mt][nt][r]);
      mx[r] = m;
    }
#pragma unroll
    for (int d = 1; d < 16; d <<= 1)
#pragma unroll
      for (int r = 0; r < 4; ++r) mx[r] = fmaxf(mx[r], __shfl_xor(mx[r], d));
    f32x4 sum = {};
#pragma unroll
    for (int nt = 0; nt < 8; ++nt)
#pragma unroll
      for (int r = 0; r < 4; ++r) {
        float p = __expf(s[mt][nt][r] - mx[r]);
        s[mt][nt][r] = p;
        sum[r] += p;
      }
#pragma unroll
    for (int d = 1; d < 16; d <<= 1)
#pragma unroll
      for (int r = 0; r < 4; ++r) sum[r] += __shfl_xor(sum[r], d);
    f32x4 inv;
#pragma unroll
    for (int r = 0; r < 4; ++r) inv[r] = 1.0f / sum[r];
#pragma unroll
    for (int nt = 0; nt < 8; ++nt)
#pragma unroll
      for (int r = 0; r < 4; ++r) {
        int rl = w * 32 + mt * 16 + 4 * lg + r;
        int c = nt * 16 + lr;
        p_lds[rl][c] = f2bf(s[mt][nt][r] * inv[r]);
      }
  }
  __syncthreads();

  // phase 3: prealign = P @ query_e[b]  (K = Q = 128), cols 0..299
  const u16* qtp = qeT + (long)b * QETN * NQ;
#pragma unroll 1
  for (int nt = 0; nt < 19; ++nt) {
    f32x4 acc0 = {}, acc1 = {};
#pragma unroll
    for (int ks = 0; ks < NQ; ks += 32) {
      bf16x8 a0 = *(const bf16x8*)(&p_lds[w * 32 + lr][ks + 8 * lg]);
      bf16x8 a1 = *(const bf16x8*)(&p_lds[w * 32 + 16 + lr][ks + 8 * lg]);
      bf16x8 bb = *(const bf16x8*)(qtp + (long)(nt * 16 + lr) * NQ + ks + 8 * lg);
      acc0 = MFMA16(a0, bb, acc0);
      acc1 = MFMA16(a1, bb, acc1);
    }
    int col = nt * 16 + lr;
    if (col < NE) {
#pragma unroll
      for (int r = 0; r < 4; ++r) {
        long rl0 = (long)b * ND + chunk * 128 + w * 32 + 4 * lg + r;
        doc_out[rl0 * DOC_W + 300 + col] = acc0[r];
        doc_out[(rl0 + 16) * DOC_W + 300 + col] = acc1[r];
      }
    }
  }
}

extern "C" void kernel_launch(void* const* d_in, const int* in_sizes, int n_in,
                              void* d_out, int out_size, void* d_ws, size_t ws_size,
                              hipStream_t stream) {
  // Size-based dispatch (verified R3/R4: identical to dict order; kept for robustness).
  const int *query_tok = nullptr, *doc_tok = nullptr, *doc_pos = nullptr, *doc_ner = nullptr;
  const float *doc_fea = nullptr, *word_emb = nullptr, *proj_w = nullptr,
              *proj_b = nullptr, *pos_emb = nullptr, *ner_emb = nullptr;
  int n65536 = 0;
  for (int i = 0; i < n_in; ++i) {
    switch (in_sizes[i]) {
      case 15000000: word_emb  = (const float*)d_in[i]; break;  // 50000*300
      case 262144:   doc_fea   = (const float*)d_in[i]; break;  // 64*1024*4
      case 76800:    proj_w    = (const float*)d_in[i]; break;  // 300*256
      case 8192:     query_tok = (const int*)d_in[i];   break;  // 64*128
      case 256:      proj_b    = (const float*)d_in[i]; break;
      case 672:      pos_emb   = (const float*)d_in[i]; break;  // 56*12
      case 152:      ner_emb   = (const float*)d_in[i]; break;  // 19*8
      case 65536:                                               // 64*1024 ints
        if (n65536 == 0)      doc_tok = (const int*)d_in[i];
        else if (n65536 == 1) doc_pos = (const int*)d_in[i];
        else                  doc_ner = (const int*)d_in[i];
        ++n65536; break;
      default: break;
    }
  }

  float* out = (float*)d_out;
  float* q_out   = out;                         // [B*Q][300] f32
  float* doc_out = out + (size_t)NB * NQ * NE;  // [B*D][624] f32

  char* ws = (char*)d_ws;
  u16* Wt     = (u16*)ws; ws += (size_t)NH * KP * 2;        // 160 KB
  u16* q_proj = (u16*)ws; ws += (size_t)NB * NQ * NH * 2;   // 4 MB
  u16* d_proj = (u16*)ws; ws += (size_t)NB * ND * NH * 2;   // 32 MB
  u16* qeT    = (u16*)ws; ws += (size_t)NB * QETN * NQ * 2; // 4.75 MB

  k_prepw<<<dim3((NH * KP + 255) / 256), dim3(256), 0, stream>>>(proj_w, Wt);
  k_embed<<<dim3(NB * NQ * 75 / 256), dim3(256), 0, stream>>>(
      query_tok, word_emb, q_out, (long)NE, NB * NQ);
  k_embed<<<dim3(NB * ND * 75 / 256), dim3(256), 0, stream>>>(
      doc_tok, word_emb, doc_out, (long)DOC_W, NB * ND);
  k_extras<<<dim3(NB * ND * 24 / 256), dim3(256), 0, stream>>>(
      doc_ner, doc_pos, doc_fea, ner_emb, pos_emb, doc_out);
  k_qet<<<dim3(2, NB), dim3(256), 0, stream>>>(q_out, qeT);
  k_proj<<<dim3(NB * NQ / 64), dim3(256), 0, stream>>>(
      q_out, (long)NE, Wt, proj_b, q_proj);
  k_proj<<<dim3(NB * ND / 64), dim3(256), 0, stream>>>(
      doc_out, (long)DOC_W, Wt, proj_b, d_proj);
  k_attn<<<dim3(ND / 128, NB), dim3(256), 0, stream>>>(d_proj, q_proj, qeT, doc_out);
}

// Round 6
// 171.627 us; speedup vs baseline: 1.2743x; 1.1087x over previous
//
#include <hip/hip_runtime.h>
#include <hip/hip_bf16.h>

typedef unsigned short u16;
typedef __attribute__((ext_vector_type(8))) short bf16x8;
typedef __attribute__((ext_vector_type(4))) float f32x4;

#define MFMA16(a, b, c) __builtin_amdgcn_mfma_f32_16x16x32_bf16((a), (b), (c), 0, 0, 0)

#define NB 64
#define ND 1024
#define NQ 128
#define NE 300
#define NH 256
#define KP 320
#define QETN 304
#define DOC_W 624

static __device__ __forceinline__ u16 f2bf(float f) {
  union { __bf16 h; u16 u; } c; c.h = (__bf16)f; return c.u;
}

static __device__ __forceinline__ bf16x8 cvt8(const float* p) {
  float4 f0 = *(const float4*)p;
  float4 f1 = *(const float4*)(p + 4);
  union { bf16x8 v; u16 u[8]; } r;
  r.u[0] = f2bf(f0.x); r.u[1] = f2bf(f0.y); r.u[2] = f2bf(f0.z); r.u[3] = f2bf(f0.w);
  r.u[4] = f2bf(f1.x); r.u[5] = f2bf(f1.y); r.u[6] = f2bf(f1.z); r.u[7] = f2bf(f1.w);
  return r.v;
}

// ---- Wt[n][k] = bf16(proj_w[k][n]), zero rows for k in [300,320) ----
__global__ void k_prepw(const float* __restrict__ w, u16* __restrict__ wt) {
  int idx = blockIdx.x * 256 + threadIdx.x;
  if (idx >= NH * KP) return;
  int n = idx / KP, k = idx % KP;
  wt[idx] = (k < NE) ? f2bf(w[k * NH + n]) : (u16)0;
}

// ---- query embedding gather -> q_out [8192][300] f32 ----
__global__ void k_embed_q(const int* __restrict__ tok, const float* __restrict__ table,
                          float* __restrict__ out_f) {
  int idx = blockIdx.x * 256 + threadIdx.x;
  int row = idx / 75, j = idx % 75;
  int k = j * 4;
  float4 v = {0.f, 0.f, 0.f, 0.f};
  int t = tok[row];
  if (t != 0) v = *(const float4*)(table + (long)t * NE + k);
  *(float4*)(out_f + (long)row * NE + k) = v;
}

// ---- doc embedding (cols 0:300) + ner/pos/fea (cols 600:624) in one pass ----
__global__ void k_embed_doc(const int* __restrict__ tok, const float* __restrict__ table,
                            const int* __restrict__ ner, const int* __restrict__ pos,
                            const float* __restrict__ fea,
                            const float* __restrict__ ner_emb, const float* __restrict__ pos_emb,
                            float* __restrict__ doc_out) {
  int idx = blockIdx.x * 256 + threadIdx.x;
  int row = idx / 81, j = idx % 81;
  if (j < 75) {
    int k = j * 4;
    float4 v = {0.f, 0.f, 0.f, 0.f};
    int t = tok[row];
    if (t != 0) v = *(const float4*)(table + (long)t * NE + k);
    *(float4*)(doc_out + (long)row * DOC_W + k) = v;
  } else {
    int c0 = (j - 75) * 4;
    float4 v;
    float* vp = (float*)&v;
#pragma unroll
    for (int u = 0; u < 4; ++u) {
      int c = c0 + u;
      float x;
      if (c < 8)       { int t = ner[row]; x = t ? ner_emb[t * 8 + c] : 0.f; }
      else if (c < 20) { int t = pos[row]; x = t ? pos_emb[t * 12 + (c - 8)] : 0.f; }
      else             { x = fea[(long)row * 4 + (c - 20)]; }
      vp[u] = x;
    }
    *(float4*)(doc_out + (long)row * DOC_W + 600 + c0) = v;
  }
}

// ---- q-side combo: blocks [0,128) = q_proj GEMM; [128,256) = qeT transpose ----
__launch_bounds__(256)
__global__ void k_qside(const float* __restrict__ qo, const u16* __restrict__ Wt,
                        const float* __restrict__ bias,
                        u16* __restrict__ qP, u16* __restrict__ qet) {
  __shared__ u16 T[64][314];
  int tid = threadIdx.x;
  if (blockIdx.x < 128) {
    // q_proj: relu(q_out @ W + b) -> bf16 [8192][256]; 64 rows x 256 cols per block
    int l = tid & 63, w = tid >> 6;
    int lr = l & 15, lg = l >> 4;
    int bm = blockIdx.x * 64 + (w & 1) * 32;
    int bn = (w >> 1) * 128;
    f32x4 acc[2][8] = {};
    const float* xp0 = qo + (long)(bm + lr) * NE + 8 * lg;
    const float* xp1 = xp0 + 16 * NE;
    const u16* wp = Wt + (long)(bn + lr) * KP + 8 * lg;
#pragma unroll 2
    for (int ks = 0; ks < KP; ks += 32) {
      bf16x8 a0 = cvt8(xp0 + ks);
      bf16x8 a1 = cvt8(xp1 + ks);
#pragma unroll
      for (int nt = 0; nt < 8; ++nt) {
        bf16x8 b0 = *(const bf16x8*)(wp + (long)nt * 16 * KP + ks);
        acc[0][nt] = MFMA16(a0, b0, acc[0][nt]);
        acc[1][nt] = MFMA16(a1, b0, acc[1][nt]);
      }
    }
#pragma unroll
    for (int nt = 0; nt < 8; ++nt) {
      int col = bn + nt * 16 + lr;
      float bv = bias[col];
#pragma unroll
      for (int mt = 0; mt < 2; ++mt)
#pragma unroll
        for (int r = 0; r < 4; ++r) {
          int row = bm + mt * 16 + 4 * lg + r;
          float v = acc[mt][nt][r] + bv;
          v = v > 0.f ? v : 0.f;
          qP[(long)row * NH + col] = f2bf(v);
        }
    }
  } else {
    // qeT[b][n][k] = bf16(q_out[b*128+k][n]); n in [300,304) -> 0
    int bx = blockIdx.x - 128;
    int b = bx >> 1, k0 = (bx & 1) * 64;
    const float* src = qo + ((long)b * NQ + k0) * NE;
    for (int i = tid; i < 64 * 75; i += 256) {
      int row = i / 75, j = (i % 75) * 4;
      float4 f = *(const float4*)(src + (long)row * NE + j);
      T[row][j]     = f2bf(f.x); T[row][j + 1] = f2bf(f.y);
      T[row][j + 2] = f2bf(f.z); T[row][j + 3] = f2bf(f.w);
    }
    __syncthreads();
    u16* dst = qet + (long)b * QETN * NQ + k0;
    for (int i = tid; i < QETN * 16; i += 256) {
      int n = i / 16, kq = (i % 16) * 4;
      u16 v[4] = {0, 0, 0, 0};
      if (n < NE) {
        v[0] = T[kq][n]; v[1] = T[kq + 1][n]; v[2] = T[kq + 2][n]; v[3] = T[kq + 3][n];
      }
      *(uint2*)(dst + (long)n * NQ + kq) = *(const uint2*)v;
    }
  }
}

// ---- fused: d_proj (into LDS) -> scores -> softmax -> prealign ----
// block = (chunk, b): 128 doc rows. LDS dp[128][264] (67.6 KB), p_lds overlays dp.
__launch_bounds__(256, 2)
__global__ void k_fused(float* doc_out, const u16* __restrict__ Wt,
                        const float* __restrict__ bias,
                        const u16* __restrict__ qP, const u16* __restrict__ qeT) {
  __shared__ __align__(16) u16 dp[128][264];
  u16 (*p_lds)[136] = (u16 (*)[136]) & dp[0][0];
  int b = blockIdx.y, chunk = blockIdx.x;
  int l = threadIdx.x & 63, w = threadIdx.x >> 6;
  int lr = l & 15, lg = l >> 4;
  long grow = (long)b * ND + chunk * 128 + w * 32;  // this wave's first doc row

  // stage 1: d_proj rows [grow, grow+32) -> dp[w*32 ..][0:256), bf16
  {
    f32x4 acc[2][16] = {};
    const float* xp0 = doc_out + (grow + lr) * DOC_W + 8 * lg;
    const float* xp1 = xp0 + 16 * DOC_W;
    const u16* wp = Wt + (long)lr * KP + 8 * lg;
#pragma unroll 2
    for (int ks = 0; ks < KP; ks += 32) {
      bf16x8 a0 = cvt8(xp0 + ks);  // cols 300:320 are junk * zero Wt rows -> 0
      bf16x8 a1 = cvt8(xp1 + ks);
#pragma unroll
      for (int nt = 0; nt < 16; ++nt) {
        bf16x8 b0 = *(const bf16x8*)(wp + (long)nt * 16 * KP + ks);
        acc[0][nt] = MFMA16(a0, b0, acc[0][nt]);
        acc[1][nt] = MFMA16(a1, b0, acc[1][nt]);
      }
    }
#pragma unroll
    for (int nt = 0; nt < 16; ++nt) {
      int col = nt * 16 + lr;
      float bv = bias[col];
#pragma unroll
      for (int mt = 0; mt < 2; ++mt)
#pragma unroll
        for (int r = 0; r < 4; ++r) {
          float v = acc[mt][nt][r] + bv;
          v = v > 0.f ? v : 0.f;
          dp[w * 32 + mt * 16 + 4 * lg + r][col] = f2bf(v);
        }
    }
  }
  // each wave reads only rows it wrote -> no barrier before stage 2

  // stage 2: scores S[32][128] per wave, K = 256, A from dp, B from global qP
  f32x4 s[2][8] = {};
  {
    const u16* qpp = qP + ((long)b * NQ + lr) * NH + 8 * lg;
#pragma unroll
    for (int ks = 0; ks < NH; ks += 32) {
      bf16x8 a0 = *(const bf16x8*)&dp[w * 32 + lr][ks + 8 * lg];
      bf16x8 a1 = *(const bf16x8*)&dp[w * 32 + 16 + lr][ks + 8 * lg];
#pragma unroll
      for (int nt = 0; nt < 8; ++nt) {
        bf16x8 bb = *(const bf16x8*)(qpp + (long)nt * 16 * NH + ks);
        s[0][nt] = MFMA16(a0, bb, s[0][nt]);
        s[1][nt] = MFMA16(a1, bb, s[1][nt]);
      }
    }
  }
  __syncthreads();  // all dp reads complete before p_lds overlay is written

  // stage 3: softmax over q, write P bf16 to p_lds (own rows only)
#pragma unroll
  for (int mt = 0; mt < 2; ++mt) {
    f32x4 mx;
#pragma unroll
    for (int r = 0; r < 4; ++r) {
      float m = s[mt][0][r];
#pragma unroll
      for (int nt = 1; nt < 8; ++nt) m = fmaxf(m, s[mt][nt][r]);
      mx[r] = m;
    }
#pragma unroll
    for (int d = 1; d < 16; d <<= 1)
#pragma unroll
      for (int r = 0; r < 4; ++r) mx[r] = fmaxf(mx[r], __shfl_xor(mx[r], d));
    f32x4 sum = {};
#pragma unroll
    for (int nt = 0; nt < 8; ++nt)
#pragma unroll
      for (int r = 0; r < 4; ++r) {
        float p = __expf(s[mt][nt][r] - mx[r]);
        s[mt][nt][r] = p;
        sum[r] += p;
      }
#pragma unroll
    for (int d = 1; d < 16; d <<= 1)
#pragma unroll
      for (int r = 0; r < 4; ++r) sum[r] += __shfl_xor(sum[r], d);
    f32x4 inv;
#pragma unroll
    for (int r = 0; r < 4; ++r) inv[r] = 1.0f / sum[r];
#pragma unroll
    for (int nt = 0; nt < 8; ++nt)
#pragma unroll
      for (int r = 0; r < 4; ++r) {
        int rl = w * 32 + mt * 16 + 4 * lg + r;
        int c = nt * 16 + lr;
        p_lds[rl][c] = f2bf(s[mt][nt][r] * inv[r]);
      }
  }
  // own-row reads in stage 4 -> no second barrier

  // stage 4: prealign = P @ query_e[b] (K = 128) -> doc_out cols 300:600 f32
  const u16* qtp = qeT + (long)b * QETN * NQ;
#pragma unroll 1
  for (int nt = 0; nt < 19; ++nt) {
    f32x4 acc0 = {}, acc1 = {};
#pragma unroll
    for (int ks = 0; ks < NQ; ks += 32) {
      bf16x8 a0 = *(const bf16x8*)&p_lds[w * 32 + lr][ks + 8 * lg];
      bf16x8 a1 = *(const bf16x8*)&p_lds[w * 32 + 16 + lr][ks + 8 * lg];
      bf16x8 bb = *(const bf16x8*)(qtp + (long)(nt * 16 + lr) * NQ + ks + 8 * lg);
      acc0 = MFMA16(a0, bb, acc0);
      acc1 = MFMA16(a1, bb, acc1);
    }
    int col = nt * 16 + lr;
    if (col < NE) {
#pragma unroll
      for (int r = 0; r < 4; ++r) {
        long rl0 = grow + 4 * lg + r;
        doc_out[rl0 * DOC_W + 300 + col] = acc0[r];
        doc_out[(rl0 + 16) * DOC_W + 300 + col] = acc1[r];
      }
    }
  }
}

extern "C" void kernel_launch(void* const* d_in, const int* in_sizes, int n_in,
                              void* d_out, int out_size, void* d_ws, size_t ws_size,
                              hipStream_t stream) {
  // Size-based dispatch (R3/R4: identical to dict order; kept for robustness).
  const int *query_tok = nullptr, *doc_tok = nullptr, *doc_pos = nullptr, *doc_ner = nullptr;
  const float *doc_fea = nullptr, *word_emb = nullptr, *proj_w = nullptr,
              *proj_b = nullptr, *pos_emb = nullptr, *ner_emb = nullptr;
  int n65536 = 0;
  for (int i = 0; i < n_in; ++i) {
    switch (in_sizes[i]) {
      case 15000000: word_emb  = (const float*)d_in[i]; break;  // 50000*300
      case 262144:   doc_fea   = (const float*)d_in[i]; break;  // 64*1024*4
      case 76800:    proj_w    = (const float*)d_in[i]; break;  // 300*256
      case 8192:     query_tok = (const int*)d_in[i];   break;  // 64*128
      case 256:      proj_b    = (const float*)d_in[i]; break;
      case 672:      pos_emb   = (const float*)d_in[i]; break;  // 56*12
      case 152:      ner_emb   = (const float*)d_in[i]; break;  // 19*8
      case 65536:                                               // 64*1024 ints
        if (n65536 == 0)      doc_tok = (const int*)d_in[i];
        else if (n65536 == 1) doc_pos = (const int*)d_in[i];
        else                  doc_ner = (const int*)d_in[i];
        ++n65536; break;
      default: break;
    }
  }

  float* out = (float*)d_out;
  float* q_out   = out;                         // [B*Q][300] f32
  float* doc_out = out + (size_t)NB * NQ * NE;  // [B*D][624] f32

  char* ws = (char*)d_ws;
  u16* Wt  = (u16*)ws; ws += (size_t)NH * KP * 2;        // 160 KB
  u16* qP  = (u16*)ws; ws += (size_t)NB * NQ * NH * 2;   // 4 MB
  u16* qeT = (u16*)ws; ws += (size_t)NB * QETN * NQ * 2; // 4.75 MB

  k_prepw<<<dim3(320), dim3(256), 0, stream>>>(proj_w, Wt);
  k_embed_q<<<dim3(2400), dim3(256), 0, stream>>>(query_tok, word_emb, q_out);
  k_embed_doc<<<dim3(20736), dim3(256), 0, stream>>>(
      doc_tok, word_emb, doc_ner, doc_pos, doc_fea, ner_emb, pos_emb, doc_out);
  k_qside<<<dim3(256), dim3(256), 0, stream>>>(q_out, Wt, proj_b, qP, qeT);
  k_fused<<<dim3(ND / 128, NB), dim3(256), 0, stream>>>(doc_out, Wt, proj_b, qP, qeT);
}